// Round 6
// baseline (203.698 us; speedup 1.0000x reference)
//
#include <hip/hip_runtime.h>
#include <cfloat>
#include <cmath>

// Problem constants (fixed by the reference setup).
#define BB 64
#define NN 32768
#define CC 2
#define KK 10
#define S_SL 32                // slices of N -> 64 candidate slots/row, 1 per lane
#define SLICE (NN / S_SL)      // 1024 columns per slice
#define TPM 256                // match kernel threads (4 waves; waves 1-3 only do Phase 1)
#define VLARGE 1.0e6
#define KEY_MAX 0xFFFFFFFFFFFFFFFFull
#define BND_MARGIN 1.0e-4      // safety margin on f32-nomination vs f64-decision slack

__device__ __forceinline__ float fsig(float x) {
    // fast sigmoid: nomination-only (all greedy decisions re-evaluated in f64)
    return __fdividef(1.0f, 1.0f + __expf(-x));
}
__device__ __forceinline__ double dsig(float x) { return 1.0 / (1.0 + exp(-(double)x)); }
__device__ __forceinline__ double dsoftplus(double x) {
    return fmax(x, 0.0) + log1p(exp(-fabs(x)));
}
// cost >= 0 (sum of squares form), so f32 bits are monotone as u32.
__device__ __forceinline__ unsigned long long packkey(float v, int c) {
    return ((unsigned long long)__float_as_uint(v) << 32) | (unsigned int)c;
}
__device__ __forceinline__ void merge2(unsigned long long& a1, unsigned long long& a2,
                                       unsigned long long b1, unsigned long long b2) {
    unsigned long long lo = a1 < b1 ? a1 : b1;
    unsigned long long hi = a1 < b1 ? b1 : a1;
    unsigned long long mb = a2 < b2 ? a2 : b2;
    a2 = hi < mb ? hi : mb;
    a1 = lo;
}
// f32 nomination cost — IDENTICAL expression in scan and rescan paths.
__device__ __forceinline__ float costf(float xs, float xe, float xc0, float xc1,
                                       float ffs, float ffe, int cls, int pres) {
    if (!pres) return (float)VLARGE;
    const float s = fsig(xs), e = fsig(xe), q0 = fsig(xc0), q1 = fsig(xc1);
    const float t0 = q0 - 1.0f, t1 = q1 - 1.0f;
    const float cp = (cls == 0) ? fmaf(t0, t0, q1 * q1) : fmaf(t1, t1, q0 * q0);
    const float d0 = s - ffs, d1 = e - ffe;
    return fmaf(d0, d0, fmaf(d1, d1, cp));
}
// f64 exact cost — decisions match numpy reference (verified r1/r3/r4: absmax 0).
__device__ __forceinline__ double eval64(const float* ps, const float* pe, const float* pc,
                                         double fs, double fe, int cls, int pres, int col) {
    if (!pres) return VLARGE;
    const double s  = dsig(ps[col]);
    const double e  = dsig(pe[col]);
    const double q0 = dsig(pc[2 * col]);
    const double q1 = dsig(pc[2 * col + 1]);
    const double d0 = s - fs, d1 = e - fe;
    const double sc = (cls == 0) ? q0 : q1;
    return d0 * d0 + d1 * d1 + (q0 * q0 + q1 * q1 - 2.0 * sc + 1.0);
}

// ---------------- Kernel A: one wave per (slice, batch); per-row top-2 per slice ----------------
// (verbatim from round 4 — proven correct)
__global__ __launch_bounds__(64)
void scan_kernel(const float* __restrict__ p_start, const float* __restrict__ p_end,
                 const float* __restrict__ p_cls, const float* __restrict__ gt,
                 ulonglong2* __restrict__ cand) {
    const int sl = blockIdx.x, b = blockIdx.y, j = threadIdx.x;
    const float2* ps2 = (const float2*)(p_start + (size_t)b * NN);
    const float2* pe2 = (const float2*)(p_end   + (size_t)b * NN);
    const float4* pc4 = (const float4*)(p_cls   + (size_t)b * NN * CC);

    float rfs[KK], rfe[KK]; int rcl[KK], rpres[KK];
    #pragma unroll
    for (int k = 0; k < KK; k++) {
        float f0 = gt[((size_t)b * KK + k) * 3 + 0];
        float f1 = gt[((size_t)b * KK + k) * 3 + 1];
        float f2 = gt[((size_t)b * KK + k) * 3 + 2];
        int pres = !(isnan(f0) || isnan(f1) || isnan(f2));
        if (isnan(f0)) f0 = 0.0f;
        if (isnan(f1)) f1 = 0.0f;
        if (isnan(f2)) f2 = 0.0f;
        int ci = (int)f2; ci = ci < 0 ? 0 : (ci > CC - 1 ? CC - 1 : ci);
        rfs[k] = f0; rfe[k] = f1; rcl[k] = ci; rpres[k] = pres;
    }

    float v1[KK], v2[KK]; int c1[KK], c2[KK];
    #pragma unroll
    for (int k = 0; k < KK; k++) { v1[k] = FLT_MAX; v2[k] = FLT_MAX; c1[k] = 0x7fffffff; c2[k] = 0x7fffffff; }

    const int base = sl * SLICE;
    #pragma unroll
    for (int it = 0; it < SLICE / 128; it++) {
        const int pidx = (base >> 1) + it * 64 + j;
        const float2 sv = ps2[pidx];
        const float2 ev = pe2[pidx];
        const float4 cv = pc4[pidx];
        #pragma unroll
        for (int h = 0; h < 2; h++) {
            const int n = 2 * pidx + h;
            const float s  = fsig(h ? sv.y : sv.x);
            const float e  = fsig(h ? ev.y : ev.x);
            const float q0 = fsig(h ? cv.z : cv.x);
            const float q1 = fsig(h ? cv.w : cv.y);
            const float t0 = q0 - 1.0f, t1 = q1 - 1.0f;
            const float cp0 = fmaf(t0, t0, q1 * q1);
            const float cp1 = fmaf(t1, t1, q0 * q0);
            #pragma unroll
            for (int k = 0; k < KK; k++) {
                const float d0 = s - rfs[k], d1 = e - rfe[k];
                float cost = fmaf(d0, d0, fmaf(d1, d1, (rcl[k] == 0) ? cp0 : cp1));
                if (!rpres[k]) cost = (float)VLARGE;
                const bool lt1 = cost < v1[k], lt2 = cost < v2[k];
                v2[k] = lt2 ? (lt1 ? v1[k] : cost) : v2[k];
                c2[k] = lt2 ? (lt1 ? c1[k] : n)    : c2[k];
                v1[k] = lt1 ? cost : v1[k];
                c1[k] = lt1 ? n    : c1[k];
            }
        }
    }

    unsigned long long k1[KK], k2[KK];
    #pragma unroll
    for (int k = 0; k < KK; k++) { k1[k] = packkey(v1[k], c1[k]); k2[k] = packkey(v2[k], c2[k]); }
    #pragma unroll
    for (int off = 1; off < 64; off <<= 1) {
        #pragma unroll
        for (int k = 0; k < KK; k++) {
            unsigned long long o1 = __shfl_xor(k1[k], off, 64);
            unsigned long long o2 = __shfl_xor(k2[k], off, 64);
            merge2(k1[k], k2[k], o1, o2);
        }
    }
    if (j == 0) {
        #pragma unroll
        for (int k = 0; k < KK; k++) {
            ulonglong2 pk; pk.x = k1[k]; pk.y = k2[k];
            cand[((size_t)b * S_SL + sl) * KK + k] = pk;
        }
    }
}

// ---------------- Kernel B: parallel f64 eval + stateless single-butterfly greedy ----------------
__global__ __launch_bounds__(TPM)
void match_kernel(const float* __restrict__ p_start, const float* __restrict__ p_end,
                  const float* __restrict__ p_cls, const float* __restrict__ p_conf,
                  const float* __restrict__ gt, const ulonglong2* __restrict__ cand,
                  double* __restrict__ partials) {
    const int b = blockIdx.x, tid = threadIdx.x;
    const int j = tid & 63, wv = tid >> 6;
    const float* ps  = p_start + (size_t)b * NN;
    const float* pe  = p_end   + (size_t)b * NN;
    const float* pc  = p_cls   + (size_t)b * NN * CC;
    const float* pcf = p_conf  + (size_t)b * NN;

    __shared__ double l_cost[KK][64];
    __shared__ int    l_col[KK][64];
    __shared__ double gfs[KK], gfe[KK];
    __shared__ int    gcls[KK], gpres[KK];

    // ---- Phase 0: gt load + clean ----
    if (tid < KK) {
        float f0 = gt[((size_t)b * KK + tid) * 3 + 0];
        float f1 = gt[((size_t)b * KK + tid) * 3 + 1];
        float f2 = gt[((size_t)b * KK + tid) * 3 + 2];
        int pres = !(isnan(f0) || isnan(f1) || isnan(f2));
        if (isnan(f0)) f0 = 0.0f;
        if (isnan(f1)) f1 = 0.0f;
        if (isnan(f2)) f2 = 0.0f;
        int ci = (int)f2; ci = ci < 0 ? 0 : (ci > CC - 1 ? CC - 1 : ci);
        gfs[tid] = (double)f0; gfe[tid] = (double)f1;
        gcls[tid] = ci; gpres[tid] = pres;
    }
    __syncthreads();

    // ---- Phase 1: f64 eval of all K*64 candidates, 256 threads in parallel ----
    for (int idx = tid; idx < KK * 64; idx += TPM) {
        const int r = idx >> 6, jj = idx & 63, sl = jj >> 1;
        ulonglong2 pk = cand[((size_t)b * S_SL + sl) * KK + r];
        const unsigned long long key = (jj & 1) ? pk.y : pk.x;
        const int c = (int)(unsigned int)(key & 0xffffffffull);
        l_cost[r][jj] = eval64(ps, pe, pc, gfs[r], gfe[r], gcls[r], gpres[r], c);
        l_col[r][jj]  = c;
    }
    __syncthreads();
    if (wv != 0) return;   // waves 1-3 done; wave 0 owns the rest (LDS persists)

    // ---- Phase 2: greedy matching, wave 0, STATELESS per-step reduction ----
    // lane j = slot (slice j>>1, rank j&1). col >= 0: real candidate with exact
    // f64 val. col == -1: slot killed -> val is a LOWER BOUND on all hidden
    // columns of this slice (hidden >= slice-2nd >= killed value, minus margin).
    double val[KK]; int col[KK];
    #pragma unroll
    for (int r = 0; r < KK; r++) { val[r] = l_cost[r][j]; col[r] = l_col[r][j]; }

    const int s_my = j >> 1;
    int cons[KK], prow[KK], pcolv[KK], pvalid[KK];
    #pragma unroll
    for (int r = 0; r < KK; r++) cons[r] = -1;

    for (int step = 0; step < KK; step++) {
        double bv = DBL_MAX; int brow = 0x7fffffff, bcol = 0x7fffffff;
        for (int guard = 0; guard < 1024; guard++) {
            // per-lane min over rows: key (v, row, col); bounds tagged col = -2 - slice
            double lv = DBL_MAX; int lr = 0x7fffffff, lc = 0x7fffffff;
            #pragma unroll
            for (int r = 0; r < KK; r++) {
                double v = val[r]; int c = col[r];
                if (c < 0) { v -= BND_MARGIN; c = -2 - s_my; }   // DBL_MAX absorbs the margin
                if (v < lv || (v == lv && (r < lr || (r == lr && c < lc)))) { lv = v; lr = r; lc = c; }
            }
            // one lexicographic butterfly per pick attempt (matches flat row-major argmin)
            #pragma unroll
            for (int off = 1; off < 64; off <<= 1) {
                const double ov = __shfl_xor(lv, off, 64);
                const int   orr = __shfl_xor(lr, off, 64);
                const int   oc  = __shfl_xor(lc, off, 64);
                if (ov < lv || (ov == lv && (orr < lr || (orr == lr && oc < lc)))) {
                    lv = ov; lr = orr; lc = oc;
                }
            }
            bv = lv; brow = lr; bcol = lc;
            if (bcol >= 0 || bv == DBL_MAX) break;   // real winner (or nothing left)

            // a bound won -> exact rescan of (row brow, slice ss); realifies both slots. Rare.
            const int ss  = -2 - bcol;
            const float ffs = (float)gfs[brow], ffe = (float)gfe[brow];
            const int   cb  = gcls[brow], pb = gpres[brow];
            unsigned long long r1 = KEY_MAX, r2 = KEY_MAX;
            const int cbase = ss * SLICE;
            for (int t = j; t < SLICE; t += 64) {
                const int n = cbase + t;
                bool used = false;
                #pragma unroll
                for (int u = 0; u < KK; u++) used |= (u < step) && (cons[u] == n);
                const float cst = costf(ps[n], pe[n], pc[2 * n], pc[2 * n + 1], ffs, ffe, cb, pb);
                const unsigned long long kk = used ? KEY_MAX : packkey(cst, n);
                if (kk < r2) { if (kk < r1) { r2 = r1; r1 = kk; } else { r2 = kk; } }
            }
            #pragma unroll
            for (int off = 1; off < 64; off <<= 1) {
                const unsigned long long o1 = __shfl_xor(r1, off, 64);
                const unsigned long long o2 = __shfl_xor(r2, off, 64);
                merge2(r1, r2, o1, o2);
            }
            const int cA = (int)(unsigned int)(r1 & 0xffffffffull);
            const int cB = (int)(unsigned int)(r2 & 0xffffffffull);
            const double vA = eval64(ps, pe, pc, gfs[brow], gfe[brow], cb, pb, cA);
            const double vB = eval64(ps, pe, pc, gfs[brow], gfe[brow], cb, pb, cB);
            #pragma unroll
            for (int r = 0; r < KK; r++) {
                if (r != brow) continue;
                if (j == 2 * ss)     { val[r] = vA; col[r] = cA; }
                if (j == 2 * ss + 1) { val[r] = vB; col[r] = cB; }
            }
        }

        prow[step]   = brow;
        pcolv[step]  = bcol;
        pvalid[step] = (bv < VLARGE * 0.5) && (bcol >= 0) && (brow < KK);
        cons[step]   = bcol;

        // remove the matched row everywhere; kill the consumed column (slot -> bound)
        #pragma unroll
        for (int r = 0; r < KK; r++) {
            if (r == brow) val[r] = DBL_MAX;
            if (bcol >= 0 && col[r] == bcol) col[r] = -1;
        }
    }

    // ---- Phase 3: losses, one pick per lane (wave 0) ----
    double loss = 0.0, m = 0.0;
    if (j < KK && pvalid[j]) {
        const int r = prow[j], cidx = pcolv[j];
        const double ss = dsig(ps[cidx]);
        const double se = dsig(pe[cidx]);
        const double gs = gfs[r], ge = gfe[r];
        const double d0 = ss - gs, d1 = se - ge;
        double acc = d0 * d0 + d1 * d1;

        const double l0 = (double)pc[2 * cidx];
        const double l1 = (double)pc[2 * cidx + 1];
        const double y0 = (gcls[r] == 0) ? 1.0 : 0.0;
        const double y1 = 1.0 - y0;
        acc += y0 * dsoftplus(-l0) + (1.0 - y0) * dsoftplus(l0)
             + y1 * dsoftplus(-l1) + (1.0 - y1) * dsoftplus(l1);

        const double a1 = fmin(ss, se), b1 = fmax(ss, se);
        const double a2 = fmin(gs, ge), b2 = fmax(gs, ge);
        const double inter = fmax(0.0, fmin(b1, b2) - fmax(a1, a2));
        const double uni   = fmax(1e-8, fmax(b1, b2) - fmin(a1, a2));
        const double iou   = inter / uni;
        const double dcf   = dsig(pcf[cidx]) - iou;
        acc += dcf * dcf;
        loss = acc; m = 1.0;
    }
    #pragma unroll
    for (int off = 1; off < 64; off <<= 1) {
        loss += __shfl_xor(loss, off, 64);
        m    += __shfl_xor(m, off, 64);
    }
    if (j == 0) { partials[b * 2 + 0] = loss; partials[b * 2 + 1] = m; }
}

__global__ void finalize_kernel(const double* __restrict__ partials,
                                float* __restrict__ out, int out_size) {
    const int t = threadIdx.x;
    for (int i = t; i < out_size; i += 64) out[i] = 0.0f;
    double s = partials[t * 2 + 0];
    double m = partials[t * 2 + 1];
    for (int off = 32; off > 0; off >>= 1) {
        s += __shfl_down(s, off, 64);
        m += __shfl_down(m, off, 64);
    }
    if (t == 0) {
        const double total = s / (m + 1e-8);
        out[0] = (float)(m > 0.0 ? total : 0.0);
    }
}

extern "C" void kernel_launch(void* const* d_in, const int* in_sizes, int n_in,
                              void* d_out, int out_size, void* d_ws, size_t ws_size,
                              hipStream_t stream) {
    const float* p_start = (const float*)d_in[0];  // (B, N)
    const float* p_end   = (const float*)d_in[1];  // (B, N)
    const float* p_cls   = (const float*)d_in[2];  // (B, N, C)
    const float* p_conf  = (const float*)d_in[3];  // (B, N)
    const float* gt      = (const float*)d_in[4];  // (B, K, 3)

    ulonglong2* cand     = (ulonglong2*)d_ws;      // B*S*K*16 B = 320 KiB
    double*     partials = (double*)((char*)d_ws + (size_t)BB * S_SL * KK * sizeof(ulonglong2));

    scan_kernel<<<dim3(S_SL, BB), 64, 0, stream>>>(p_start, p_end, p_cls, gt, cand);
    match_kernel<<<BB, TPM, 0, stream>>>(p_start, p_end, p_cls, p_conf, gt, cand, partials);
    finalize_kernel<<<1, 64, 0, stream>>>(partials, (float*)d_out, out_size);
}

// Round 7
// 148.053 us; speedup vs baseline: 1.3758x; 1.3758x over previous
//
#include <hip/hip_runtime.h>
#include <cfloat>
#include <cmath>

// Problem constants (fixed by the reference setup).
#define BB 64
#define NN 32768
#define CC 2
#define KK 10
#define S_SL 32                // slices of N -> 64 candidate slots/row, 1 per lane
#define SLICE (NN / S_SL)      // 1024 columns per slice
#define TPM 256                // match kernel threads (4 waves; waves 1-3 only do eval)
#define VLARGE 1.0e6
#define KEY_MAX 0xFFFFFFFFFFFFFFFFull
#define BND_MARGIN 1.0e-3      // covers f32 nomination error vs f64 decisions (~2e-5)

__device__ __forceinline__ double dsig(float x) { return 1.0 / (1.0 + exp(-(double)x)); }
__device__ __forceinline__ double dsoftplus(double x) {
    return fmax(x, 0.0) + log1p(exp(-fabs(x)));
}
// clamped cost >= 0, so f32 bits are monotone as u32 -> (cost, col) packs sortable.
__device__ __forceinline__ unsigned long long packkey(float v, int c) {
    return ((unsigned long long)__float_as_uint(v) << 32) | (unsigned int)c;
}
__device__ __forceinline__ void merge2(unsigned long long& a1, unsigned long long& a2,
                                       unsigned long long b1, unsigned long long b2) {
    unsigned long long lo = a1 < b1 ? a1 : b1;
    unsigned long long hi = a1 < b1 ? b1 : a1;
    unsigned long long mb = a2 < b2 ? a2 : b2;
    a2 = hi < mb ? hi : mb;
    a1 = lo;
}
// Shared f32 column terms + row cost — IDENTICAL codegen in scan and rescan,
// so the slice-2nd bound is consistent between the two.
__device__ __forceinline__ void colterms(float sraw, float eraw, float q0raw, float q1raw,
                                         float& s, float& e, float& u0, float& u1) {
    s = __fdividef(1.0f, 1.0f + __expf(-sraw));
    e = __fdividef(1.0f, 1.0f + __expf(-eraw));
    const float q0 = __fdividef(1.0f, 1.0f + __expf(-q0raw));
    const float q1 = __fdividef(1.0f, 1.0f + __expf(-q1raw));
    const float se2 = fmaf(s, s, e * e);
    const float t0 = q0 - 1.0f, t1 = q1 - 1.0f;
    u0 = se2 + fmaf(t0, t0, q1 * q1);   // class-0 full cost, minus row terms
    u1 = se2 + fmaf(t1, t1, q0 * q0);   // class-1
}
__device__ __forceinline__ float rowcost(float s, float e, float u0, float u1,
                                         float m0, float m1, float ckv, int cls, int pres) {
    float c = fmaf(m0, s, fmaf(m1, e, ((cls == 0) ? u0 : u1) + ckv));
    c = fmaxf(c, 0.0f);                 // rearrangement can go ~-2e-6; keep bits sortable
    return pres ? c : (float)VLARGE;
}
// f64 exact cost — decisions match numpy reference (verified r1/r3/r4/r6: absmax 0).
__device__ __forceinline__ double eval64(const float* ps, const float* pe, const float* pc,
                                         double fs, double fe, int cls, int pres, int col) {
    if (!pres) return VLARGE;
    const double s  = dsig(ps[col]);
    const double e  = dsig(pe[col]);
    const double q0 = dsig(pc[2 * col]);
    const double q1 = dsig(pc[2 * col + 1]);
    const double d0 = s - fs, d1 = e - fe;
    const double sc = (cls == 0) ? q0 : q1;
    return d0 * d0 + d1 * d1 + (q0 * q0 + q1 * q1 - 2.0 * sc + 1.0);
}

// ---------------- Kernel A: one wave per (slice, batch); per-row top-2 per slice ----------------
__global__ __launch_bounds__(64)
void scan_kernel(const float* __restrict__ p_start, const float* __restrict__ p_end,
                 const float* __restrict__ p_cls, const float* __restrict__ gt,
                 ulonglong2* __restrict__ cand) {
    const int sl = blockIdx.x, b = blockIdx.y, j = threadIdx.x;
    const float2* ps2 = (const float2*)(p_start + (size_t)b * NN);
    const float2* pe2 = (const float2*)(p_end   + (size_t)b * NN);
    const float4* pc4 = (const float4*)(p_cls   + (size_t)b * NN * CC);

    float m0[KK], m1[KK], ck[KK]; int rcl[KK], rpres[KK];
    #pragma unroll
    for (int k = 0; k < KK; k++) {
        float f0 = gt[((size_t)b * KK + k) * 3 + 0];
        float f1 = gt[((size_t)b * KK + k) * 3 + 1];
        float f2 = gt[((size_t)b * KK + k) * 3 + 2];
        int pres = !(isnan(f0) || isnan(f1) || isnan(f2));
        if (isnan(f0)) f0 = 0.0f;
        if (isnan(f1)) f1 = 0.0f;
        if (isnan(f2)) f2 = 0.0f;
        int ci = (int)f2; ci = ci < 0 ? 0 : (ci > CC - 1 ? CC - 1 : ci);
        m0[k] = -2.0f * f0; m1[k] = -2.0f * f1;
        ck[k] = fmaf(f0, f0, f1 * f1);
        rcl[k] = ci; rpres[k] = pres;
    }

    float v1[KK], v2[KK]; int c1[KK], c2[KK];
    #pragma unroll
    for (int k = 0; k < KK; k++) { v1[k] = FLT_MAX; v2[k] = FLT_MAX; c1[k] = 0x7fffffff; c2[k] = 0x7fffffff; }

    const int base = sl * SLICE;
    #pragma unroll
    for (int it = 0; it < SLICE / 128; it++) {   // 8 iters, 2 columns per lane each
        const int pidx = (base >> 1) + it * 64 + j;
        const float2 sv = ps2[pidx];
        const float2 ev = pe2[pidx];
        const float4 cv = pc4[pidx];
        #pragma unroll
        for (int h = 0; h < 2; h++) {
            const int n = 2 * pidx + h;
            float s, e, u0, u1;
            colterms(h ? sv.y : sv.x, h ? ev.y : ev.x,
                     h ? cv.z : cv.x, h ? cv.w : cv.y, s, e, u0, u1);
            #pragma unroll
            for (int k = 0; k < KK; k++) {
                const float cost = rowcost(s, e, u0, u1, m0[k], m1[k], ck[k], rcl[k], rpres[k]);
                // n ascends per thread -> strict < keeps lowest col on ties
                const bool lt1 = cost < v1[k], lt2 = cost < v2[k];
                v2[k] = lt2 ? (lt1 ? v1[k] : cost) : v2[k];
                c2[k] = lt2 ? (lt1 ? c1[k] : n)    : c2[k];
                v1[k] = lt1 ? cost : v1[k];
                c1[k] = lt1 ? n    : c1[k];
            }
        }
    }

    unsigned long long k1[KK], k2[KK];
    #pragma unroll
    for (int k = 0; k < KK; k++) { k1[k] = packkey(v1[k], c1[k]); k2[k] = packkey(v2[k], c2[k]); }
    #pragma unroll
    for (int off = 1; off < 64; off <<= 1) {
        #pragma unroll
        for (int k = 0; k < KK; k++) {
            unsigned long long o1 = __shfl_xor(k1[k], off, 64);
            unsigned long long o2 = __shfl_xor(k2[k], off, 64);
            merge2(k1[k], k2[k], o1, o2);
        }
    }
    if (j == 0) {
        #pragma unroll
        for (int k = 0; k < KK; k++) {
            ulonglong2 pk; pk.x = k1[k]; pk.y = k2[k];
            cand[((size_t)b * S_SL + sl) * KK + k] = pk;
        }
    }
}

// ---------------- Kernel B: parallel f64 eval + stateless greedy with LOOSE slice-2nd bounds ----
__global__ __launch_bounds__(TPM)
void match_kernel(const float* __restrict__ p_start, const float* __restrict__ p_end,
                  const float* __restrict__ p_cls, const float* __restrict__ p_conf,
                  const float* __restrict__ gt, const ulonglong2* __restrict__ cand,
                  double* __restrict__ partials) {
    const int b = blockIdx.x, tid = threadIdx.x;
    const int j = tid & 63, wv = tid >> 6;
    const float* ps  = p_start + (size_t)b * NN;
    const float* pe  = p_end   + (size_t)b * NN;
    const float* pc  = p_cls   + (size_t)b * NN * CC;
    const float* pcf = p_conf  + (size_t)b * NN;

    __shared__ double l_cost[KK][64];
    __shared__ int    l_col[KK][64];
    __shared__ double l_bnd[KK][S_SL];   // slice-2nd f32 value (f64) - margin
    __shared__ double gfs[KK], gfe[KK];
    __shared__ int    gcls[KK], gpres[KK];

    // ---- Phase 0: gt load + clean ----
    if (tid < KK) {
        float f0 = gt[((size_t)b * KK + tid) * 3 + 0];
        float f1 = gt[((size_t)b * KK + tid) * 3 + 1];
        float f2 = gt[((size_t)b * KK + tid) * 3 + 2];
        int pres = !(isnan(f0) || isnan(f1) || isnan(f2));
        if (isnan(f0)) f0 = 0.0f;
        if (isnan(f1)) f1 = 0.0f;
        if (isnan(f2)) f2 = 0.0f;
        int ci = (int)f2; ci = ci < 0 ? 0 : (ci > CC - 1 ? CC - 1 : ci);
        gfs[tid] = (double)f0; gfe[tid] = (double)f1;
        gcls[tid] = ci; gpres[tid] = pres;
    }
    __syncthreads();

    // ---- Phase 1: f64 eval of all K*64 candidates, 256 threads in parallel ----
    for (int idx = tid; idx < KK * 64; idx += TPM) {
        const int r = idx >> 6, jj = idx & 63, sl = jj >> 1;
        ulonglong2 pk = cand[((size_t)b * S_SL + sl) * KK + r];
        const unsigned long long key = (jj & 1) ? pk.y : pk.x;
        int c = (int)(unsigned int)(key & 0xffffffffull);
        if (c < 0 || c >= NN) c = 0;   // cannot trigger; OOB-crash guard only
        l_cost[r][jj] = eval64(ps, pe, pc, gfs[r], gfe[r], gcls[r], gpres[r], c);
        l_col[r][jj]  = c;
        if (jj & 1)
            l_bnd[r][sl] = (double)__uint_as_float((unsigned int)(key >> 32)) - BND_MARGIN;
    }
    __syncthreads();
    if (wv != 0) return;   // waves 1-3 done; wave 0 owns the rest (LDS persists)

    // ---- Phase 2: greedy matching, wave 0, stateless per-attempt reduction ----
    // lane j = slot (slice j>>1, rank j&1). col >= 0: real candidate (exact f64 val).
    // col == -1: dead. When BOTH slots of a slice are dead, the even lane presents
    // the slice bound (hidden columns >= slice-2nd f32 - margin).
    const int s_my = j >> 1;
    double val[KK]; int col[KK]; double bnd[KK];
    #pragma unroll
    for (int r = 0; r < KK; r++) {
        val[r] = l_cost[r][j]; col[r] = l_col[r][j]; bnd[r] = l_bnd[r][s_my];
    }

    unsigned act = (1u << KK) - 1;
    int cons[KK], prow[KK], pcolv[KK], pvalid[KK];
    #pragma unroll
    for (int r = 0; r < KK; r++) cons[r] = -1;

    for (int step = 0; step < KK; step++) {
        double bv = DBL_MAX; int brow = 0x7fffffff, bcol = 0x7fffffff;
        // guard 64 > max possible both-dead slices (<=9 kills -> <=4 slices x 10 rows);
        // each rescan permanently realifies one, so this terminates provably.
        for (int guard = 0; guard < 64; guard++) {
            double lv = DBL_MAX; int lr = 0x7fffffff, lc = 0x7fffffff;
            #pragma unroll
            for (int r = 0; r < KK; r++) {
                if (!((act >> r) & 1)) continue;
                const int pcold = __shfl(col[r], j ^ 1, 64);
                const bool mine  = (col[r] >= 0);
                const bool bound = !mine && (pcold < 0) && ((j & 1) == 0);
                const double v = mine ? val[r] : (bound ? bnd[r] : DBL_MAX);
                const int    c = mine ? col[r] : (bound ? (-2 - s_my) : 0x7fffffff);
                if (v < lv || (v == lv && (r < lr || (r == lr && c < lc)))) {
                    lv = v; lr = r; lc = c;
                }
            }
            #pragma unroll
            for (int off = 1; off < 64; off <<= 1) {
                const double ov = __shfl_xor(lv, off, 64);
                const int   orr = __shfl_xor(lr, off, 64);
                const int   oc  = __shfl_xor(lc, off, 64);
                if (ov < lv || (ov == lv && (orr < lr || (orr == lr && oc < lc)))) {
                    lv = ov; lr = orr; lc = oc;
                }
            }
            bv = lv; brow = lr; bcol = lc;
            if (bcol >= 0 || bv == DBL_MAX) break;   // real winner (or nothing left)

            // a slice bound won -> exact top-2 rescan of (row brow, slice ss). Rare.
            const int ss = -2 - bcol;
            const float ffs = (float)gfs[brow], ffe = (float)gfe[brow];
            const int   cb  = gcls[brow], pb = gpres[brow];
            const float m0b = -2.0f * ffs, m1b = -2.0f * ffe;
            const float ckb = fmaf(ffs, ffs, ffe * ffe);
            unsigned long long r1 = KEY_MAX, r2 = KEY_MAX;
            const int cbase = ss * SLICE;
            for (int t = j; t < SLICE; t += 64) {
                const int n = cbase + t;
                bool used = false;
                #pragma unroll
                for (int u = 0; u < KK; u++) used |= (cons[u] == n);
                float s, e, u0, u1;
                colterms(ps[n], pe[n], pc[2 * n], pc[2 * n + 1], s, e, u0, u1);
                const float cst = rowcost(s, e, u0, u1, m0b, m1b, ckb, cb, pb);
                const unsigned long long kk = used ? KEY_MAX : packkey(cst, n);
                if (kk < r2) { if (kk < r1) { r2 = r1; r1 = kk; } else { r2 = kk; } }
            }
            #pragma unroll
            for (int off = 1; off < 64; off <<= 1) {
                const unsigned long long o1 = __shfl_xor(r1, off, 64);
                const unsigned long long o2 = __shfl_xor(r2, off, 64);
                merge2(r1, r2, o1, o2);
            }
            int cA = (int)(unsigned int)(r1 & 0xffffffffull);
            int cB = (int)(unsigned int)(r2 & 0xffffffffull);
            if (cA < 0 || cA >= NN) cA = 0;
            if (cB < 0 || cB >= NN) cB = 0;
            const double vA = (r1 == KEY_MAX) ? DBL_MAX
                : eval64(ps, pe, pc, gfs[brow], gfe[brow], cb, pb, cA);
            const double vB = (r2 == KEY_MAX) ? DBL_MAX
                : eval64(ps, pe, pc, gfs[brow], gfe[brow], cb, pb, cB);
            const double nb = (r2 == KEY_MAX) ? DBL_MAX
                : (double)__uint_as_float((unsigned int)(r2 >> 32)) - BND_MARGIN;
            #pragma unroll
            for (int r = 0; r < KK; r++) {
                if (r != brow) continue;
                if (j == 2 * ss)     { val[r] = vA; col[r] = (r1 == KEY_MAX) ? -1 : cA; }
                if (j == 2 * ss + 1) { val[r] = vB; col[r] = (r2 == KEY_MAX) ? -1 : cB; }
                if (s_my == ss) bnd[r] = nb;   // hidden >= rescan 2nd - margin
            }
        }

        prow[step]   = brow;
        pcolv[step]  = bcol;
        pvalid[step] = (bv < VLARGE * 0.5) && (bcol >= 0) && (brow < KK);
        cons[step]   = (bcol >= 0) ? bcol : -1;
        if (brow < KK) act &= ~(1u << brow);
        else break;                          // nothing left at all

        // kill the consumed column everywhere
        if (bcol >= 0) {
            #pragma unroll
            for (int r = 0; r < KK; r++)
                if (col[r] == bcol) col[r] = -1;
        }
    }

    // ---- Phase 3: losses, one pick per lane (wave 0) ----
    double loss = 0.0, m = 0.0;
    if (j < KK && pvalid[j]) {
        const int r = prow[j], cidx = pcolv[j];
        const double ss = dsig(ps[cidx]);
        const double se = dsig(pe[cidx]);
        const double gs = gfs[r], ge = gfe[r];
        const double d0 = ss - gs, d1 = se - ge;
        double acc = d0 * d0 + d1 * d1;

        const double l0 = (double)pc[2 * cidx];
        const double l1 = (double)pc[2 * cidx + 1];
        const double y0 = (gcls[r] == 0) ? 1.0 : 0.0;
        const double y1 = 1.0 - y0;
        acc += y0 * dsoftplus(-l0) + (1.0 - y0) * dsoftplus(l0)
             + y1 * dsoftplus(-l1) + (1.0 - y1) * dsoftplus(l1);

        const double a1 = fmin(ss, se), b1 = fmax(ss, se);
        const double a2 = fmin(gs, ge), b2 = fmax(gs, ge);
        const double inter = fmax(0.0, fmin(b1, b2) - fmax(a1, a2));
        const double uni   = fmax(1e-8, fmax(b1, b2) - fmin(a1, a2));
        const double iou   = inter / uni;
        const double dcf   = dsig(pcf[cidx]) - iou;
        acc += dcf * dcf;
        loss = acc; m = 1.0;
    }
    #pragma unroll
    for (int off = 1; off < 64; off <<= 1) {
        loss += __shfl_xor(loss, off, 64);
        m    += __shfl_xor(m, off, 64);
    }
    if (j == 0) { partials[b * 2 + 0] = loss; partials[b * 2 + 1] = m; }
}

__global__ void finalize_kernel(const double* __restrict__ partials,
                                float* __restrict__ out, int out_size) {
    const int t = threadIdx.x;
    for (int i = t; i < out_size; i += 64) out[i] = 0.0f;
    double s = partials[t * 2 + 0];
    double m = partials[t * 2 + 1];
    for (int off = 32; off > 0; off >>= 1) {
        s += __shfl_down(s, off, 64);
        m += __shfl_down(m, off, 64);
    }
    if (t == 0) {
        const double total = s / (m + 1e-8);
        out[0] = (float)(m > 0.0 ? total : 0.0);
    }
}

extern "C" void kernel_launch(void* const* d_in, const int* in_sizes, int n_in,
                              void* d_out, int out_size, void* d_ws, size_t ws_size,
                              hipStream_t stream) {
    const float* p_start = (const float*)d_in[0];  // (B, N)
    const float* p_end   = (const float*)d_in[1];  // (B, N)
    const float* p_cls   = (const float*)d_in[2];  // (B, N, C)
    const float* p_conf  = (const float*)d_in[3];  // (B, N)
    const float* gt      = (const float*)d_in[4];  // (B, K, 3)

    ulonglong2* cand     = (ulonglong2*)d_ws;      // B*S*K*16 B = 320 KiB
    double*     partials = (double*)((char*)d_ws + (size_t)BB * S_SL * KK * sizeof(ulonglong2));

    scan_kernel<<<dim3(S_SL, BB), 64, 0, stream>>>(p_start, p_end, p_cls, gt, cand);
    match_kernel<<<BB, TPM, 0, stream>>>(p_start, p_end, p_cls, p_conf, gt, cand, partials);
    finalize_kernel<<<1, 64, 0, stream>>>(partials, (float*)d_out, out_size);
}